// Round 1
// baseline (291.456 us; speedup 1.0000x reference)
//
#include <hip/hip_runtime.h>

// MHA forward: H=16 heads, N=2048 tokens, d_model=1024, d_k=64.
// d_out = [ out (2048x1024 f32) | p_attn (16x2048x2048 f32) ]
// All GEMMs: bf16 MFMA 16x16x32, f32 accumulate, B^T reduction pattern.

#define NTOK 2048
#define DMODEL 1024
#define NHEAD 16
#define DKH 64

typedef __attribute__((ext_vector_type(8))) short bf16x8;
typedef __attribute__((ext_vector_type(4))) float f32x4;

__device__ __forceinline__ unsigned short f2bf(float x) {
  unsigned int u = __builtin_bit_cast(unsigned int, x);
  u += 0x7fffu + ((u >> 16) & 1u);   // RNE
  return (unsigned short)(u >> 16);
}

struct GemmP {
  const void* A[3];
  const void* B[3];
  const float* bias[3];
  long long sA, sB, sC;   // per-z element strides (used when gridDim.z != 3)
  int lda, ldb, ldc;
  int M, Nn, K;
  const int* mask;
  float scale;
  void* C;
};

// Stage a ROWS x 64-element tile into LDS as bf16, row = 128 bytes,
// XOR-swizzled: lds_pos = pos ^ ((row&7)<<4)  (2-way max bank aliasing, free)
template<int ROWS, bool F32>
__device__ __forceinline__ void stage_tile(char* lds, const char* gsrc, int ld, int k0, int tid) {
  if constexpr (F32) {
    const float* src = (const float*)gsrc;
#pragma unroll
    for (int c = 0; c < ROWS / 16; ++c) {
      int cid = c * 256 + tid;
      int row = cid >> 4;
      int ck = cid & 15;                 // 16B source chunk = 4 floats
      float4 v = *(const float4*)(src + (size_t)row * ld + k0 + ck * 4);
      ushort4 h;
      h.x = f2bf(v.x); h.y = f2bf(v.y); h.z = f2bf(v.z); h.w = f2bf(v.w);
      int off = row * 128 + ((ck * 8) ^ ((row & 7) << 4));
      *(ushort4*)(lds + off) = h;
    }
  } else {
    const unsigned short* src = (const unsigned short*)gsrc;
#pragma unroll
    for (int c = 0; c < ROWS / 32; ++c) {
      int cid = c * 256 + tid;
      int row = cid >> 3;
      int ck = cid & 7;                  // 16B chunk = 8 bf16
      uint4 v = *(const uint4*)(src + (size_t)row * ld + k0 + ck * 8);
      int off = row * 128 + ((ck * 16) ^ ((row & 7) << 4));
      *(uint4*)(lds + off) = v;
    }
  }
}

__device__ __forceinline__ bf16x8 ldsfrag(const char* lds, int r, int kb) {
  int off = r * 128 + (kb ^ ((r & 7) << 4));
  return *(const bf16x8*)(lds + off);
}

// C[m,n] = scale * sum_k A[m,k]*B[n,k] + bias[n]   (both operands row-major, reduce over k)
// gridDim.z==3 -> pointer-select A/B/bias by z (QKV proj); else z*stride offsets.
template<int BM, int BN, bool AF32, bool BF32, bool OUTF32, bool MASKED>
__global__ __launch_bounds__(256) void gemm_bt(GemmP P) {
  constexpr int BK = 64;
  constexpr int WM = BM / 2, WN = BN / 2, FM = WM / 16, FN = WN / 16;
  __shared__ char ldsA[BM * 128];
  __shared__ char ldsB[BN * 128];
  const int tid = threadIdx.x;
  const int z = blockIdx.z;
  const bool sel3 = (gridDim.z == 3);
  const int zi = sel3 ? z : 0;
  const int ntn = P.Nn / BN;
  const int bm = (int)blockIdx.x / ntn;
  const int bn = (int)blockIdx.x % ntn;
  const int m0 = bm * BM, n0 = bn * BN;

  const long long zA = sel3 ? 0 : (long long)z * P.sA;
  const long long zB = sel3 ? 0 : (long long)z * P.sB;
  const char* Ab = (const char*)P.A[zi] + ((long long)m0 * P.lda + zA) * (AF32 ? 4 : 2);
  const char* Bb = (const char*)P.B[zi] + ((long long)n0 * P.ldb + zB) * (BF32 ? 4 : 2);

  f32x4 acc[FM][FN] = {};
  const int lane = tid & 63;
  const int wm = (tid >> 6) >> 1, wn = (tid >> 6) & 1;

  for (int k0 = 0; k0 < P.K; k0 += BK) {
    stage_tile<BM, AF32>(ldsA, Ab, P.lda, k0, tid);
    stage_tile<BN, BF32>(ldsB, Bb, P.ldb, k0, tid);
    __syncthreads();
#pragma unroll
    for (int kk = 0; kk < 2; ++kk) {
      const int kb = kk * 64 + ((lane >> 4) * 16);
      bf16x8 a[FM], b[FN];
#pragma unroll
      for (int i = 0; i < FM; ++i) a[i] = ldsfrag(ldsA, wm * WM + i * 16 + (lane & 15), kb);
#pragma unroll
      for (int j = 0; j < FN; ++j) b[j] = ldsfrag(ldsB, wn * WN + j * 16 + (lane & 15), kb);
#pragma unroll
      for (int i = 0; i < FM; ++i)
#pragma unroll
        for (int j = 0; j < FN; ++j)
          acc[i][j] = __builtin_amdgcn_mfma_f32_16x16x32_bf16(a[i], b[j], acc[i][j], 0, 0, 0);
    }
    __syncthreads();
  }

  char* Cb = (char*)P.C + ((long long)z * P.sC) * (OUTF32 ? 4 : 2);
  const int rbase = m0 + wm * WM + ((lane >> 4) << 2);
  const int cbase = n0 + wn * WN + (lane & 15);
#pragma unroll
  for (int j = 0; j < FN; ++j) {
    const int col = cbase + j * 16;
    const float badd = P.bias[zi] ? P.bias[zi][col] : 0.0f;
    const bool msk = MASKED ? (P.mask[col] == 0) : false;
#pragma unroll
    for (int i = 0; i < FM; ++i) {
#pragma unroll
      for (int rg = 0; rg < 4; ++rg) {
        const int row = rbase + i * 16 + rg;
        float v = acc[i][j][rg] * P.scale + badd;
        if (MASKED && msk) v = -1000000000.0f;
        if constexpr (OUTF32)
          ((float*)Cb)[(size_t)row * P.ldc + col] = v;
        else
          ((unsigned short*)Cb)[(size_t)row * P.ldc + col] = f2bf(v);
      }
    }
  }
}

// VT[h][d][n] = VP[n][h*64+d]
__global__ __launch_bounds__(256) void transpose_v(const unsigned short* __restrict__ VP,
                                                   unsigned short* __restrict__ VT) {
  __shared__ unsigned short t[64][72];
  const int h = blockIdx.y;
  const int n0 = blockIdx.x * 64;
  const int tid = threadIdx.x;
  const int rr = tid >> 3;
  const int cc = (tid & 7) * 8;
#pragma unroll
  for (int ps = 0; ps < 2; ++ps) {
    const int r = ps * 32 + rr;
    const unsigned short* src = VP + (size_t)(n0 + r) * DMODEL + h * DKH + cc;
    ushort4 a = *(const ushort4*)src;
    ushort4 b = *(const ushort4*)(src + 4);
    t[cc + 0][r] = a.x; t[cc + 1][r] = a.y; t[cc + 2][r] = a.z; t[cc + 3][r] = a.w;
    t[cc + 4][r] = b.x; t[cc + 5][r] = b.y; t[cc + 6][r] = b.z; t[cc + 7][r] = b.w;
  }
  __syncthreads();
#pragma unroll
  for (int ps = 0; ps < 2; ++ps) {
    const int d = ps * 32 + rr;
    unsigned short* dst = VT + ((size_t)h * DKH + d) * NTOK + n0 + cc;
    ushort4 a, b;
    a.x = t[d][cc + 0]; a.y = t[d][cc + 1]; a.z = t[d][cc + 2]; a.w = t[d][cc + 3];
    b.x = t[d][cc + 4]; b.y = t[d][cc + 5]; b.z = t[d][cc + 6]; b.w = t[d][cc + 7];
    *(ushort4*)dst = a;
    *(ushort4*)(dst + 4) = b;
  }
}

// in-place softmax over rows of 2048 f32 (one block per row)
__global__ __launch_bounds__(256) void softmax_rows(float* __restrict__ p) {
  float* r = p + (size_t)blockIdx.x * NTOK;
  const int tid = threadIdx.x;
  float4 v0 = ((float4*)r)[tid];
  float4 v1 = ((float4*)r)[tid + 256];
  float mx = fmaxf(fmaxf(fmaxf(v0.x, v0.y), fmaxf(v0.z, v0.w)),
                   fmaxf(fmaxf(v1.x, v1.y), fmaxf(v1.z, v1.w)));
  __shared__ float red[4];
#pragma unroll
  for (int o = 32; o > 0; o >>= 1) mx = fmaxf(mx, __shfl_xor(mx, o, 64));
  if ((tid & 63) == 0) red[tid >> 6] = mx;
  __syncthreads();
  mx = fmaxf(fmaxf(red[0], red[1]), fmaxf(red[2], red[3]));
  v0.x = __expf(v0.x - mx); v0.y = __expf(v0.y - mx);
  v0.z = __expf(v0.z - mx); v0.w = __expf(v0.w - mx);
  v1.x = __expf(v1.x - mx); v1.y = __expf(v1.y - mx);
  v1.z = __expf(v1.z - mx); v1.w = __expf(v1.w - mx);
  float s = v0.x + v0.y + v0.z + v0.w + v1.x + v1.y + v1.z + v1.w;
#pragma unroll
  for (int o = 32; o > 0; o >>= 1) s += __shfl_xor(s, o, 64);
  __syncthreads();
  if ((tid & 63) == 0) red[tid >> 6] = s;
  __syncthreads();
  const float inv = 1.0f / (red[0] + red[1] + red[2] + red[3]);
  v0.x *= inv; v0.y *= inv; v0.z *= inv; v0.w *= inv;
  v1.x *= inv; v1.y *= inv; v1.z *= inv; v1.w *= inv;
  ((float4*)r)[tid] = v0;
  ((float4*)r)[tid + 256] = v1;
}

extern "C" void kernel_launch(void* const* d_in, const int* in_sizes, int n_in,
                              void* d_out, int out_size, void* d_ws, size_t ws_size,
                              hipStream_t stream) {
  (void)in_sizes; (void)n_in; (void)out_size; (void)ws_size;
  const float* query = (const float*)d_in[0];
  const float* key_  = (const float*)d_in[1];
  const float* value = (const float*)d_in[2];
  const int*   mask  = (const int*)d_in[3];
  const float* Wq = (const float*)d_in[4];
  const float* bq = (const float*)d_in[5];
  const float* Wk = (const float*)d_in[6];
  const float* bk = (const float*)d_in[7];
  const float* Wv = (const float*)d_in[8];
  const float* bv = (const float*)d_in[9];
  const float* Wo = (const float*)d_in[10];
  const float* bo = (const float*)d_in[11];

  float* out = (float*)d_out;
  float* p = out + (size_t)NTOK * DMODEL;   // p_attn region (16,2048,2048)

  char* ws = (char*)d_ws;
  unsigned short* QP = (unsigned short*)(ws);                  // (2048,1024) bf16
  unsigned short* KP = (unsigned short*)(ws + (4u << 20));
  unsigned short* VP = (unsigned short*)(ws + (8u << 20));
  unsigned short* VT = (unsigned short*)(ws + (12u << 20));    // (16,64,2048) bf16
  unsigned short* XB = (unsigned short*)(ws + (16u << 20));    // (2048,1024) bf16

  // 1. QKV projections: z selects {query,Wq,bq},{key,Wk,bk},{value,Wv,bv}
  {
    GemmP P = {};
    P.A[0] = query; P.A[1] = key_; P.A[2] = value;
    P.B[0] = Wq; P.B[1] = Wk; P.B[2] = Wv;
    P.bias[0] = bq; P.bias[1] = bk; P.bias[2] = bv;
    P.sA = 0; P.sB = 0; P.sC = (long long)NTOK * DMODEL;
    P.lda = DMODEL; P.ldb = DMODEL; P.ldc = DMODEL;
    P.M = NTOK; P.Nn = DMODEL; P.K = DMODEL;
    P.mask = nullptr; P.scale = 1.0f; P.C = QP;
    gemm_bt<64, 128, true, true, false, false>
        <<<dim3((NTOK / 64) * (DMODEL / 128), 1, 3), 256, 0, stream>>>(P);
  }
  // 2. V transpose per head
  transpose_v<<<dim3(NTOK / 64, NHEAD), 256, 0, stream>>>(VP, VT);
  // 3. scores = Q Kᵀ / 8, mask epilogue, f32 into p region (z = head)
  {
    GemmP P = {};
    P.A[0] = QP; P.B[0] = KP; P.bias[0] = nullptr;
    P.sA = DKH; P.sB = DKH; P.sC = (long long)NTOK * NTOK;
    P.lda = DMODEL; P.ldb = DMODEL; P.ldc = NTOK;
    P.M = NTOK; P.Nn = NTOK; P.K = DKH;
    P.mask = mask; P.scale = 0.125f; P.C = p;
    gemm_bt<128, 128, false, false, true, true>
        <<<dim3((NTOK / 128) * (NTOK / 128), 1, NHEAD), 256, 0, stream>>>(P);
  }
  // 4. softmax rows in place
  softmax_rows<<<NHEAD * NTOK, 256, 0, stream>>>(p);
  // 5. x = P V   (A = p f32 -> bf16 at staging; B = VT)
  {
    GemmP P = {};
    P.A[0] = p; P.B[0] = VT; P.bias[0] = nullptr;
    P.sA = (long long)NTOK * NTOK; P.sB = (long long)DKH * NTOK; P.sC = DKH;
    P.lda = NTOK; P.ldb = NTOK; P.ldc = DMODEL;
    P.M = NTOK; P.Nn = DKH; P.K = NTOK;
    P.mask = nullptr; P.scale = 1.0f; P.C = XB;
    gemm_bt<128, 64, true, false, false, false>
        <<<dim3((NTOK / 128) * (DKH / 64), 1, NHEAD), 256, 0, stream>>>(P);
  }
  // 6. out = X Woᵀ + bo
  {
    GemmP P = {};
    P.A[0] = XB; P.B[0] = Wo; P.bias[0] = bo;
    P.sA = 0; P.sB = 0; P.sC = 0;
    P.lda = DMODEL; P.ldb = DMODEL; P.ldc = DMODEL;
    P.M = NTOK; P.Nn = DMODEL; P.K = DMODEL;
    P.mask = nullptr; P.scale = 1.0f; P.C = out;
    gemm_bt<64, 128, false, true, true, false>
        <<<dim3((NTOK / 64) * (DMODEL / 128), 1, 1), 256, 0, stream>>>(P);
  }
}

// Round 2
// 170.926 us; speedup vs baseline: 1.7052x; 1.7052x over previous
//
#include <hip/hip_runtime.h>

// MHA forward: H=16 heads, N=2048 tokens, d_model=1024, d_k=64.
// d_out = [ out (2048x1024 f32) | p_attn (16x2048x2048 f32) ]
// Pipeline: QKV proj (bf16 MFMA) -> V transpose -> fused attn
// (QK^T + softmax + p-write + PV, two-pass over K, p written ONCE) -> out proj.

#define NTOK 2048
#define DMODEL 1024
#define NHEAD 16
#define DKH 64

typedef __attribute__((ext_vector_type(8))) short bf16x8;
typedef __attribute__((ext_vector_type(4))) float f32x4;

__device__ __forceinline__ unsigned short f2bf(float x) {
  unsigned int u = __builtin_bit_cast(unsigned int, x);
  u += 0x7fffu + ((u >> 16) & 1u);   // RNE
  return (unsigned short)(u >> 16);
}

struct GemmP {
  const void* A[3];
  const void* B[3];
  const float* bias[3];
  long long sA, sB, sC;
  int lda, ldb, ldc;
  int M, Nn, K;
  const int* mask;
  float scale;
  void* C;
};

// Stage a ROWS x 64-element tile into LDS as bf16, row = 128 bytes,
// XOR-swizzled: lds_pos = pos ^ ((row&7)<<4)
template<int ROWS, bool F32>
__device__ __forceinline__ void stage_tile(char* lds, const char* gsrc, int ld, int k0, int tid) {
  if constexpr (F32) {
    const float* src = (const float*)gsrc;
#pragma unroll
    for (int c = 0; c < ROWS / 16; ++c) {
      int cid = c * 256 + tid;
      int row = cid >> 4;
      int ck = cid & 15;
      float4 v = *(const float4*)(src + (size_t)row * ld + k0 + ck * 4);
      ushort4 h;
      h.x = f2bf(v.x); h.y = f2bf(v.y); h.z = f2bf(v.z); h.w = f2bf(v.w);
      int off = row * 128 + ((ck * 8) ^ ((row & 7) << 4));
      *(ushort4*)(lds + off) = h;
    }
  } else {
    const unsigned short* src = (const unsigned short*)gsrc;
#pragma unroll
    for (int c = 0; c < ROWS / 32; ++c) {
      int cid = c * 256 + tid;
      int row = cid >> 3;
      int ck = cid & 7;
      uint4 v = *(const uint4*)(src + (size_t)row * ld + k0 + ck * 8);
      int off = row * 128 + ((ck * 16) ^ ((row & 7) << 4));
      *(uint4*)(lds + off) = v;
    }
  }
}

// Stage 64 rows x 128 bf16 (256B rows), XOR-swizzled
__device__ __forceinline__ void stage_v256(char* lds, const unsigned short* src, int ld, int tid) {
#pragma unroll
  for (int c = 0; c < 4; ++c) {
    int cid = c * 256 + tid;
    int row = cid >> 4;
    int ck = cid & 15;
    uint4 v = *(const uint4*)(src + (size_t)row * ld + ck * 8);
    int off = row * 256 + ((ck * 16) ^ ((row & 7) << 4));
    *(uint4*)(lds + off) = v;
  }
}

__device__ __forceinline__ bf16x8 ldsfrag(const char* lds, int r, int kb) {
  return *(const bf16x8*)(lds + r * 128 + (kb ^ ((r & 7) << 4)));
}
__device__ __forceinline__ bf16x8 ldsfrag256(const char* lds, int r, int kb) {
  return *(const bf16x8*)(lds + r * 256 + (kb ^ ((r & 7) << 4)));
}

// C[m,n] = scale * sum_k A[m,k]*B[n,k] + bias[n]
template<int BM, int BN, bool AF32, bool BF32, bool OUTF32, bool MASKED>
__global__ __launch_bounds__(256) void gemm_bt(GemmP P) {
  constexpr int BK = 64;
  constexpr int WM = BM / 2, WN = BN / 2, FM = WM / 16, FN = WN / 16;
  __shared__ char ldsA[BM * 128];
  __shared__ char ldsB[BN * 128];
  const int tid = threadIdx.x;
  const int z = blockIdx.z;
  const bool sel3 = (gridDim.z == 3);
  const int zi = sel3 ? z : 0;
  const int ntn = P.Nn / BN;
  const int bm = (int)blockIdx.x / ntn;
  const int bn = (int)blockIdx.x % ntn;
  const int m0 = bm * BM, n0 = bn * BN;

  const long long zA = sel3 ? 0 : (long long)z * P.sA;
  const long long zB = sel3 ? 0 : (long long)z * P.sB;
  const char* Ab = (const char*)P.A[zi] + ((long long)m0 * P.lda + zA) * (AF32 ? 4 : 2);
  const char* Bb = (const char*)P.B[zi] + ((long long)n0 * P.ldb + zB) * (BF32 ? 4 : 2);

  f32x4 acc[FM][FN] = {};
  const int lane = tid & 63;
  const int wm = (tid >> 6) >> 1, wn = (tid >> 6) & 1;

  for (int k0 = 0; k0 < P.K; k0 += BK) {
    stage_tile<BM, AF32>(ldsA, Ab, P.lda, k0, tid);
    stage_tile<BN, BF32>(ldsB, Bb, P.ldb, k0, tid);
    __syncthreads();
#pragma unroll
    for (int kk = 0; kk < 2; ++kk) {
      const int kb = kk * 64 + ((lane >> 4) * 16);
      bf16x8 a[FM], b[FN];
#pragma unroll
      for (int i = 0; i < FM; ++i) a[i] = ldsfrag(ldsA, wm * WM + i * 16 + (lane & 15), kb);
#pragma unroll
      for (int j = 0; j < FN; ++j) b[j] = ldsfrag(ldsB, wn * WN + j * 16 + (lane & 15), kb);
#pragma unroll
      for (int i = 0; i < FM; ++i)
#pragma unroll
        for (int j = 0; j < FN; ++j)
          acc[i][j] = __builtin_amdgcn_mfma_f32_16x16x32_bf16(a[i], b[j], acc[i][j], 0, 0, 0);
    }
    __syncthreads();
  }

  char* Cb = (char*)P.C + ((long long)z * P.sC) * (OUTF32 ? 4 : 2);
  const int rbase = m0 + wm * WM + ((lane >> 4) << 2);
  const int cbase = n0 + wn * WN + (lane & 15);
#pragma unroll
  for (int j = 0; j < FN; ++j) {
    const int col = cbase + j * 16;
    const float badd = P.bias[zi] ? P.bias[zi][col] : 0.0f;
    const bool msk = MASKED ? (P.mask[col] == 0) : false;
#pragma unroll
    for (int i = 0; i < FM; ++i) {
#pragma unroll
      for (int rg = 0; rg < 4; ++rg) {
        const int row = rbase + i * 16 + rg;
        float v = acc[i][j][rg] * P.scale + badd;
        if (MASKED && msk) v = -1000000000.0f;
        if constexpr (OUTF32)
          ((float*)Cb)[(size_t)row * P.ldc + col] = v;
        else
          ((unsigned short*)Cb)[(size_t)row * P.ldc + col] = f2bf(v);
      }
    }
  }
}

// VT[h][d][n] = VP[n][h*64+d]
__global__ __launch_bounds__(256) void transpose_v(const unsigned short* __restrict__ VP,
                                                   unsigned short* __restrict__ VT) {
  __shared__ unsigned short t[64][72];
  const int h = blockIdx.y;
  const int n0 = blockIdx.x * 64;
  const int tid = threadIdx.x;
  const int rr = tid >> 3;
  const int cc = (tid & 7) * 8;
#pragma unroll
  for (int ps = 0; ps < 2; ++ps) {
    const int r = ps * 32 + rr;
    const unsigned short* src = VP + (size_t)(n0 + r) * DMODEL + h * DKH + cc;
    ushort4 a = *(const ushort4*)src;
    ushort4 b = *(const ushort4*)(src + 4);
    t[cc + 0][r] = a.x; t[cc + 1][r] = a.y; t[cc + 2][r] = a.z; t[cc + 3][r] = a.w;
    t[cc + 4][r] = b.x; t[cc + 5][r] = b.y; t[cc + 6][r] = b.z; t[cc + 7][r] = b.w;
  }
  __syncthreads();
#pragma unroll
  for (int ps = 0; ps < 2; ++ps) {
    const int d = ps * 32 + rr;
    unsigned short* dst = VT + ((size_t)h * DKH + d) * NTOK + n0 + cc;
    ushort4 a, b;
    a.x = t[d][cc + 0]; a.y = t[d][cc + 1]; a.z = t[d][cc + 2]; a.w = t[d][cc + 3];
    b.x = t[d][cc + 4]; b.y = t[d][cc + 5]; b.z = t[d][cc + 6]; b.w = t[d][cc + 7];
    *(ushort4*)dst = a;
    *(ushort4*)(dst + 4) = b;
  }
}

// Fused attention: per (q-block of 64 rows, head): two passes over K.
// Pass A: S = mfma(K,Q) swapped -> lane-local row sums of exp (no max-sub needed).
// Pass B: recompute S, p = exp*rinv -> f32x4 global store (written ONCE) +
//         bf16 LDS P-tile -> PV MFMAs -> X bf16 store.
__global__ __launch_bounds__(256) void attn_fused(const unsigned short* __restrict__ QP,
                                                  const unsigned short* __restrict__ KP,
                                                  const unsigned short* __restrict__ VT,
                                                  const int* __restrict__ mask,
                                                  float* __restrict__ p,
                                                  unsigned short* __restrict__ XB) {
  __shared__ char ldsQ[64 * 128];    // [64 m][64 dk]
  __shared__ char ldsK[128 * 128];   // [128 j][64 dk]
  __shared__ char ldsV[64 * 256];    // [64 d][128 j]
  __shared__ char ldsP[64 * 256];    // [64 m][128 j]
  const int tid = threadIdx.x;
  const int lane = tid & 63;
  const int w = tid >> 6;
  const int l15 = lane & 15, lhi = lane >> 4;
  const int h = blockIdx.y;
  const int q0 = blockIdx.x * 64;
  const int mrow = w * 16 + l15;   // this lane's m row within the block

  stage_tile<64, false>(ldsQ, (const char*)(QP + (size_t)q0 * DMODEL + h * DKH), DMODEL, 0, tid);
  __syncthreads();
  bf16x8 qf[2];
  qf[0] = ldsfrag(ldsQ, mrow, lhi * 16);
  qf[1] = ldsfrag(ldsQ, mrow, 64 + lhi * 16);

  // ---- pass A: row sums ----
  float rsum = 0.0f;
  for (int it = 0; it < 16; ++it) {
    const int j0 = it * 128;
    __syncthreads();
    stage_tile<128, false>(ldsK, (const char*)(KP + (size_t)j0 * DMODEL + h * DKH), DMODEL, 0, tid);
    __syncthreads();
    f32x4 sacc[8] = {};
#pragma unroll
    for (int kk = 0; kk < 2; ++kk) {
#pragma unroll
      for (int js = 0; js < 8; ++js) {
        bf16x8 kf = ldsfrag(ldsK, js * 16 + l15, kk * 64 + lhi * 16);
        sacc[js] = __builtin_amdgcn_mfma_f32_16x16x32_bf16(kf, qf[kk], sacc[js], 0, 0, 0);
      }
    }
#pragma unroll
    for (int js = 0; js < 8; ++js) {
      int4 mv = *(const int4*)(mask + j0 + js * 16 + lhi * 4);
      rsum += (mv.x ? __expf(sacc[js][0] * 0.125f) : 0.0f);
      rsum += (mv.y ? __expf(sacc[js][1] * 0.125f) : 0.0f);
      rsum += (mv.z ? __expf(sacc[js][2] * 0.125f) : 0.0f);
      rsum += (mv.w ? __expf(sacc[js][3] * 0.125f) : 0.0f);
    }
  }
  rsum += __shfl_xor(rsum, 16, 64);
  rsum += __shfl_xor(rsum, 32, 64);
  const float rinv = 1.0f / rsum;

  // ---- pass B: write p, accumulate PV ----
  float* prow = p + ((size_t)h * NTOK + q0 + mrow) * NTOK;
  f32x4 xacc[4] = {};
  for (int it = 0; it < 16; ++it) {
    const int j0 = it * 128;
    __syncthreads();
    stage_tile<128, false>(ldsK, (const char*)(KP + (size_t)j0 * DMODEL + h * DKH), DMODEL, 0, tid);
    stage_v256(ldsV, VT + (size_t)h * DKH * NTOK + j0, NTOK, tid);
    __syncthreads();
    f32x4 sacc[8] = {};
#pragma unroll
    for (int kk = 0; kk < 2; ++kk) {
#pragma unroll
      for (int js = 0; js < 8; ++js) {
        bf16x8 kf = ldsfrag(ldsK, js * 16 + l15, kk * 64 + lhi * 16);
        sacc[js] = __builtin_amdgcn_mfma_f32_16x16x32_bf16(kf, qf[kk], sacc[js], 0, 0, 0);
      }
    }
#pragma unroll
    for (int js = 0; js < 8; ++js) {
      int4 mv = *(const int4*)(mask + j0 + js * 16 + lhi * 4);
      float4 e;
      e.x = mv.x ? __expf(sacc[js][0] * 0.125f) * rinv : 0.0f;
      e.y = mv.y ? __expf(sacc[js][1] * 0.125f) * rinv : 0.0f;
      e.z = mv.z ? __expf(sacc[js][2] * 0.125f) * rinv : 0.0f;
      e.w = mv.w ? __expf(sacc[js][3] * 0.125f) * rinv : 0.0f;
      *(float4*)(prow + j0 + js * 16 + lhi * 4) = e;
      ushort4 pb;
      pb.x = f2bf(e.x); pb.y = f2bf(e.y); pb.z = f2bf(e.z); pb.w = f2bf(e.w);
      const int jl = (js * 16 + lhi * 4) * 2;
      *(ushort4*)(ldsP + mrow * 256 + (jl ^ ((mrow & 7) << 4))) = pb;
    }
    __syncthreads();
#pragma unroll
    for (int jk = 0; jk < 4; ++jk) {
      bf16x8 pf = ldsfrag256(ldsP, mrow, jk * 64 + lhi * 16);
#pragma unroll
      for (int dd = 0; dd < 4; ++dd) {
        bf16x8 vf = ldsfrag256(ldsV, dd * 16 + l15, jk * 64 + lhi * 16);
        xacc[dd] = __builtin_amdgcn_mfma_f32_16x16x32_bf16(vf, pf, xacc[dd], 0, 0, 0);
      }
    }
  }

  // X[m][d]: lane holds d = dd*16 + lhi*4 + reg, m = mrow  -> packed bf16x4 store
  unsigned short* xrow = XB + (size_t)(q0 + mrow) * DMODEL + h * DKH;
#pragma unroll
  for (int dd = 0; dd < 4; ++dd) {
    ushort4 xb;
    xb.x = f2bf(xacc[dd][0]); xb.y = f2bf(xacc[dd][1]);
    xb.z = f2bf(xacc[dd][2]); xb.w = f2bf(xacc[dd][3]);
    *(ushort4*)(xrow + dd * 16 + lhi * 4) = xb;
  }
}

extern "C" void kernel_launch(void* const* d_in, const int* in_sizes, int n_in,
                              void* d_out, int out_size, void* d_ws, size_t ws_size,
                              hipStream_t stream) {
  (void)in_sizes; (void)n_in; (void)out_size; (void)ws_size;
  const float* query = (const float*)d_in[0];
  const float* key_  = (const float*)d_in[1];
  const float* value = (const float*)d_in[2];
  const int*   mask  = (const int*)d_in[3];
  const float* Wq = (const float*)d_in[4];
  const float* bq = (const float*)d_in[5];
  const float* Wk = (const float*)d_in[6];
  const float* bk = (const float*)d_in[7];
  const float* Wv = (const float*)d_in[8];
  const float* bv = (const float*)d_in[9];
  const float* Wo = (const float*)d_in[10];
  const float* bo = (const float*)d_in[11];

  float* out = (float*)d_out;
  float* p = out + (size_t)NTOK * DMODEL;

  char* ws = (char*)d_ws;
  unsigned short* QP = (unsigned short*)(ws);
  unsigned short* KP = (unsigned short*)(ws + (4u << 20));
  unsigned short* VP = (unsigned short*)(ws + (8u << 20));
  unsigned short* VT = (unsigned short*)(ws + (12u << 20));
  unsigned short* XB = (unsigned short*)(ws + (16u << 20));

  // 1. QKV projections
  {
    GemmP P = {};
    P.A[0] = query; P.A[1] = key_; P.A[2] = value;
    P.B[0] = Wq; P.B[1] = Wk; P.B[2] = Wv;
    P.bias[0] = bq; P.bias[1] = bk; P.bias[2] = bv;
    P.sA = 0; P.sB = 0; P.sC = (long long)NTOK * DMODEL;
    P.lda = DMODEL; P.ldb = DMODEL; P.ldc = DMODEL;
    P.M = NTOK; P.Nn = DMODEL; P.K = DMODEL;
    P.mask = nullptr; P.scale = 1.0f; P.C = QP;
    gemm_bt<64, 128, true, true, false, false>
        <<<dim3((NTOK / 64) * (DMODEL / 128), 1, 3), 256, 0, stream>>>(P);
  }
  // 2. V transpose per head
  transpose_v<<<dim3(NTOK / 64, NHEAD), 256, 0, stream>>>(VP, VT);
  // 3. fused attention: p (written once) + X
  attn_fused<<<dim3(NTOK / 64, NHEAD), 256, 0, stream>>>(QP, KP, VT, mask, p, XB);
  // 4. out = X Woᵀ + bo
  {
    GemmP P = {};
    P.A[0] = XB; P.B[0] = Wo; P.bias[0] = bo;
    P.sA = 0; P.sB = 0; P.sC = 0;
    P.lda = DMODEL; P.ldb = DMODEL; P.ldc = DMODEL;
    P.M = NTOK; P.Nn = DMODEL; P.K = DMODEL;
    P.mask = nullptr; P.scale = 1.0f; P.C = out;
    gemm_bt<64, 128, false, true, true, false>
        <<<dim3((NTOK / 64) * (DMODEL / 128), 1, 1), 256, 0, stream>>>(P);
  }
}